// Round 11
// baseline (992.075 us; speedup 1.0000x reference)
//
#include <hip/hip_runtime.h>
#include <hip/hip_bf16.h>
#include <math.h>

namespace {

constexpr int kH     = 512;
constexpr int kL     = 1024;
constexpr int kB     = 64;
constexpr int kHalf  = 256;
constexpr int kV     = 32000;
constexpr int kTok   = kB * kL;     // 65536

using f32x4 = __attribute__((ext_vector_type(4))) float;
using f16x8 = __attribute__((ext_vector_type(8))) _Float16;

__device__ inline void fsplit(float v, _Float16& h, _Float16& l) {
  h = (_Float16)v;
  l = (_Float16)(v - (float)h);
}

// async 16B global->LDS (gfx950). dst must be wave-uniform base; lane l
// receives bytes [l*16, l*16+16).
typedef __attribute__((address_space(3))) void lds_vp;
typedef const __attribute__((address_space(1))) void glb_vp;
__device__ inline void gload16(const void* g, void* l) {
  __builtin_amdgcn_global_load_lds((glb_vp*)g, (lds_vp*)l, 16, 0, 0);
}

// Row-PAIR swizzled half-tile index for [128][32]-half tiles stored flat.
__device__ inline int hswz(int row, int col) {
  const int sr = row >> 1;
  const int g  = ((row & 1) << 2) | (col >> 3);
  return sr * 64 + (((g ^ (sr & 7)) << 3) | (col & 7));
}

// ---------------- positional weights
__global__ void pos_kernel(const float* __restrict__ pos_emb,
                           const float* __restrict__ pos_w,
                           const float* __restrict__ pos_b,
                           float* __restrict__ wts)
{
  int t = blockIdx.x * blockDim.x + threadIdx.x;
  if (t >= kL) return;
  float z = pos_b[0];
#pragma unroll
  for (int p = 0; p < 16; ++p) z += pos_emb[t * 16 + p] * pos_w[p];
  wts[t] = 1.f / (1.f + expf(-z));
}

// ---------------- transpose + hi/lo fp16 split: W[K][N] fp32 -> Th/Tl[N][K]
__global__ __launch_bounds__(256) void transpose_split(
    const float* __restrict__ W, _Float16* __restrict__ Th,
    _Float16* __restrict__ Tl, int N, int kshift)
{
  const int idx = blockIdx.x * 256 + threadIdx.x;
  const int K = 1 << kshift;
  const int k = idx & (K - 1);
  const int n = idx >> kshift;
  const float w = W[(size_t)k * N + n];
  const _Float16 h = (_Float16)w;
  Th[idx] = h;
  Tl[idx] = (_Float16)(w - (float)h);
}

// ---------------- mixed-precision MFMA GEMM: C = A(fp16) @ B[N,K]^T
// v14 structure: 1D XCD-banded grid + 2-phase async dbuf pipeline.
template <int EPI, int PROD>
__global__ __launch_bounds__(256) void hgemm(
    const int* __restrict__ seq, const float* __restrict__ embed,
    const _Float16* __restrict__ Ah,
    const _Float16* __restrict__ Bh, const _Float16* __restrict__ Bl,
    const float* __restrict__ bias, const float* __restrict__ bias2,
    float* __restrict__ Xout, _Float16* __restrict__ Oh, _Float16* __restrict__ Ol,
    float* __restrict__ ks, float* __restrict__ ke,
    int K, int N, int tok0c, int nyb)   // nyb = Ny/8 (token-band rows per XCD)
{
  constexpr int TILES = 1 + PROD;              // A, Bh (, Bl)
  __shared__ __align__(16) _Float16 lds[2 * TILES * 4096];  // dbuf
  const int tid  = threadIdx.x;
  const int lane = tid & 63;
  const int wv   = tid >> 6;
  const int wm   = (wv >> 1) * 64;
  const int wn   = (wv & 1) * 64;
  // XCD-banded decode (bijective for Ny%8==0)
  const int idb  = blockIdx.x;
  const int xcd  = idb & 7;
  const int j    = idb >> 3;
  const int x_   = j / nyb;
  const int yb   = j - x_ * nyb;
  const int bm0  = (xcd * nyb + yb) * 128;
  const int bn0  = x_ * 128;

  f32x4 acc[4][4];
#pragma unroll
  for (int i = 0; i < 4; ++i)
#pragma unroll
    for (int j2 = 0; j2 < 4; ++j2) acc[i][j2] = {0.f, 0.f, 0.f, 0.f};

  // async staging geometry: lane l writes phys 16B granule (super-row l>>3,
  // slot l&7); inverse-swizzled global source:
  const int sl   = lane >> 3;                 // local super-row 0..7
  const int gg   = (lane & 7) ^ sl;           // logical granule
  const int trow = wv * 16 + sl * 2 + (gg >> 2);
  const int tcol = (gg & 3) * 8;              // halves within the 32-half k-step
  const size_t brow0 = (size_t)(bn0 + trow) * K + tcol;
  const size_t brow1 = (size_t)(bn0 + trow + 64) * K + tcol;
  size_t arow0 = 0, arow1 = 0;
  const float* gAe = nullptr;
  if constexpr (EPI == 0) {
    const int sr = tid >> 1;
    const int tokrow = seq[tok0c + bm0 + sr];
    gAe = embed + (size_t)tokrow * kH + ((tid & 1) << 4);
  } else {
    arow0 = (size_t)(bm0 + trow) * K + tcol;
    arow1 = (size_t)(bm0 + trow + 64) * K + tcol;
  }
  // wave-uniform LDS bases (halves)
  const int lb0 = wv * 512;
  const int lb1 = 2048 + wv * 512;

  const int lrow = lane & 15;
  const int lk   = (lane >> 4) * 8;
  const int NT   = K >> 5;

  for (int t = 0; t <= NT; ++t) {
    const int kc = t << 5;
    float4 a0, a1, a2, a3;
    if (t < NT) {                       // issue tile-t loads (latency hides
      if constexpr (EPI == 0) {         //  under tile t-1's compute below)
        a0 = *(const float4*)(gAe + kc);
        a1 = *(const float4*)(gAe + kc + 4);
        a2 = *(const float4*)(gAe + kc + 8);
        a3 = *(const float4*)(gAe + kc + 12);
      }
      const int bo = (t & 1) * TILES * 4096;
      if constexpr (EPI != 0) {
        gload16(Ah + arow0 + kc, &lds[bo + lb0]);
        gload16(Ah + arow1 + kc, &lds[bo + lb1]);
      }
      gload16(Bh + brow0 + kc, &lds[bo + 4096 + lb0]);
      gload16(Bh + brow1 + kc, &lds[bo + 4096 + lb1]);
      if constexpr (PROD == 2) {
        gload16(Bl + brow0 + kc, &lds[bo + 8192 + lb0]);
        gload16(Bl + brow1 + kc, &lds[bo + 8192 + lb1]);
      }
    }
    if (t > 0) {                        // compute tile t-1
      const int po = ((t - 1) & 1) * TILES * 4096;
      f16x8 fBh[4], fBl[4];
#pragma unroll
      for (int ni = 0; ni < 4; ++ni) {
        fBh[ni] = *(const f16x8*)&lds[po + 4096 + hswz(wn + ni * 16 + lrow, lk)];
        if constexpr (PROD == 2)
          fBl[ni] = *(const f16x8*)&lds[po + 8192 + hswz(wn + ni * 16 + lrow, lk)];
      }
#pragma unroll
      for (int mi = 0; mi < 4; ++mi) {
        const f16x8 ah = *(const f16x8*)&lds[po + hswz(wm + mi * 16 + lrow, lk)];
#pragma unroll
        for (int ni = 0; ni < 4; ++ni) {
          acc[mi][ni] = __builtin_amdgcn_mfma_f32_16x16x32_f16(ah, fBh[ni], acc[mi][ni], 0, 0, 0);
          if constexpr (PROD == 2)
            acc[mi][ni] = __builtin_amdgcn_mfma_f32_16x16x32_f16(ah, fBl[ni], acc[mi][ni], 0, 0, 0);
        }
      }
    }
    if (t < NT) {
      if constexpr (EPI == 0) {         // manual A stage (embed gather)
        const float vv[16] = {a0.x,a0.y,a0.z,a0.w, a1.x,a1.y,a1.z,a1.w,
                              a2.x,a2.y,a2.z,a2.w, a3.x,a3.y,a3.z,a3.w};
        union { _Float16 h[16]; uint4 u[2]; } ph;
#pragma unroll
        for (int i = 0; i < 16; ++i) ph.h[i] = (_Float16)vv[i];
        const int sr = tid >> 1;
        const int sc = (tid & 1) << 4;
        const int bo = (t & 1) * TILES * 4096;
        *(uint4*)&lds[bo + hswz(sr, sc)]     = ph.u[0];
        *(uint4*)&lds[bo + hswz(sr, sc + 8)] = ph.u[1];
      }
    }
    __syncthreads();   // drains tile-t vmcnt (hidden under tile t-1 MFMA) + lgkm
  }

  const int erow0 = (lane >> 4) * 4;
  if constexpr (EPI == 0) {
#pragma unroll
    for (int mi = 0; mi < 4; ++mi)
#pragma unroll
      for (int ni = 0; ni < 4; ++ni) {
        const int gn = bn0 + wn + ni * 16 + (lane & 15);
        const float bv = bias[gn];
#pragma unroll
        for (int r = 0; r < 4; ++r) {
          const int gm = bm0 + wm + mi * 16 + erow0 + r;
          float v = fmaxf(acc[mi][ni][r] + bv, 0.f);
          Oh[(size_t)gm * N + gn] = (_Float16)v;
        }
      }
  } else if constexpr (EPI == 1) {
#pragma unroll
    for (int mi = 0; mi < 4; ++mi)
#pragma unroll
      for (int r = 0; r < 4; ++r) {
        const int gm = bm0 + wm + mi * 16 + erow0 + r;
        const int tok = seq[tok0c + gm];
        const float* er = embed + (size_t)tok * kH;
#pragma unroll
        for (int ni = 0; ni < 4; ++ni) {
          const int gn = bn0 + wn + ni * 16 + (lane & 15);
          Xout[(size_t)gm * N + gn] = acc[mi][ni][r] + bias[gn] + er[gn];
        }
      }
  } else {
    // EPI==2: write K as fp16 hi/lo pairs + per-quarter ssq partials (Xout).
    _Float16* kh_s = (_Float16*)ks;
    _Float16* kh_e = (_Float16*)ke;
    float s2[4][4];
#pragma unroll
    for (int mi = 0; mi < 4; ++mi)
#pragma unroll
      for (int r = 0; r < 4; ++r) s2[mi][r] = 0.f;
#pragma unroll
    for (int mi = 0; mi < 4; ++mi)
#pragma unroll
      for (int ni = 0; ni < 4; ++ni) {
        const int gn = bn0 + wn + ni * 16 + (lane & 15);
        const float bv = (gn < 256) ? bias[gn] : bias2[gn - 256];
        _Float16* Dh = (gn < 256) ? kh_s : kh_e;
        _Float16* Dl = (gn < 256) ? Oh : Ol;
        const int col = gn & 255;
#pragma unroll
        for (int r = 0; r < 4; ++r) {
          const int gm = bm0 + wm + mi * 16 + erow0 + r;
          const float v = acc[mi][ni][r] + bv;
          s2[mi][r] += v * v;
          _Float16 h, l;
          fsplit(v, h, l);
          Dh[(size_t)(tok0c + gm) * 256 + col] = h;
          Dl[(size_t)(tok0c + gm) * 256 + col] = l;
        }
      }
    // deterministic per-quarter partial sums: ssqPart[mat][tok][half*2 + (wv&1)]
    const int matq  = bn0 >> 8;
    const int halfq = (bn0 >> 7) & 1;
#pragma unroll
    for (int mi = 0; mi < 4; ++mi)
#pragma unroll
      for (int r = 0; r < 4; ++r) {
        float s2v = s2[mi][r];
        s2v += __shfl_xor(s2v, 1);
        s2v += __shfl_xor(s2v, 2);
        s2v += __shfl_xor(s2v, 4);
        s2v += __shfl_xor(s2v, 8);
        if ((lane & 15) == 0) {
          const int gm = bm0 + wm + mi * 16 + erow0 + r;
          Xout[((size_t)matq * kTok + (size_t)(tok0c + gm)) * 4 + halfq * 2 + (wv & 1)] = s2v;
        }
      }
  }
}

// ---------------- LayerNorm: x fp32 -> fp16 (hi only), XCD-banded tokens
__global__ __launch_bounds__(256) void ln_split(
    const float* __restrict__ x, const float* __restrict__ g,
    const float* __restrict__ bta, _Float16* __restrict__ hh, int tband)
{
  const int wid  = threadIdx.x >> 6;
  const int lane = threadIdx.x & 63;
  const int id   = blockIdx.x;
  const int ltok = (id & 7) * tband + (id >> 3) * 4 + wid;
  const float* xp = x + (size_t)ltok * kH;
  const float4 v0 = *(const float4*)(xp + lane * 8);
  const float4 v1 = *(const float4*)(xp + lane * 8 + 4);
  float s  = v0.x + v0.y + v0.z + v0.w + v1.x + v1.y + v1.z + v1.w;
  float ss = v0.x * v0.x + v0.y * v0.y + v0.z * v0.z + v0.w * v0.w +
             v1.x * v1.x + v1.y * v1.y + v1.z * v1.z + v1.w * v1.w;
#pragma unroll
  for (int m = 1; m < 64; m <<= 1) { s += __shfl_xor(s, m); ss += __shfl_xor(ss, m); }
  const float mu  = s * (1.f / kH);
  const float var = ss * (1.f / kH) - mu * mu;
  const float rs  = 1.f / sqrtf(var + 1e-5f);
  const float4 g0 = *(const float4*)(g + lane * 8);
  const float4 g1 = *(const float4*)(g + lane * 8 + 4);
  const float4 b0 = *(const float4*)(bta + lane * 8);
  const float4 b1 = *(const float4*)(bta + lane * 8 + 4);
  const float vv[8] = {v0.x, v0.y, v0.z, v0.w, v1.x, v1.y, v1.z, v1.w};
  const float gg[8] = {g0.x, g0.y, g0.z, g0.w, g1.x, g1.y, g1.z, g1.w};
  const float bb[8] = {b0.x, b0.y, b0.z, b0.w, b1.x, b1.y, b1.z, b1.w};
  union { _Float16 h[8]; uint4 u; } ph;
#pragma unroll
  for (int i = 0; i < 8; ++i) {
    const float o = (vv[i] - mu) * rs * gg[i] + bb[i];
    ph.h[i] = (_Float16)o;
  }
  *(uint4*)(hh + (size_t)ltok * kH + lane * 8) = ph.u;
}

// ---------------- T precompute: T = (I + diag(aS)*tril_strict(K K^T))^{-1}
__global__ __launch_bounds__(64) void tinv_kernel(
    const _Float16* __restrict__ khs, const _Float16* __restrict__ kls,
    const _Float16* __restrict__ khe, const _Float16* __restrict__ kle,
    const float* __restrict__ ssqP, const float* __restrict__ wts,
    _Float16* __restrict__ Tgh, _Float16* __restrict__ Tgl)
{
  __shared__ float Gs[64][68];
  const int lane = threadIdx.x;
  const int l15  = lane & 15;
  const int quad = lane >> 4;
  const int wg   = blockIdx.x;
  const int ck   = wg & 15;
  const int mat  = (wg >> 4) & 1;
  const int b    = wg >> 5;
  const _Float16* Kh = (mat ? khe : khs) + (size_t)b * (1024 * 256) + (size_t)ck * 64 * 256;
  const _Float16* Kl = (mat ? kle : kls) + (size_t)b * (1024 * 256) + (size_t)ck * 64 * 256;

  const float4 sq = *(const float4*)(ssqP + ((size_t)mat * kTok + (size_t)b * 1024 + ck * 64 + lane) * 4);
  const float w  = mat ? wts[ck * 64 + lane] : 1.f;
  const float aS = w / (sq.x + sq.y + sq.z + sq.w + 1e-6f);

  // G = K K^T via split-fp16 MFMA
  f32x4 D[16];
#pragma unroll
  for (int i = 0; i < 16; ++i) D[i] = {0.f, 0.f, 0.f, 0.f};
#pragma unroll
  for (int kit = 0; kit < 8; ++kit) {
    f16x8 fh[4], fl[4];
#pragma unroll
    for (int mi = 0; mi < 4; ++mi) {
      fh[mi] = *(const f16x8*)(Kh + (size_t)(mi * 16 + l15) * 256 + kit * 32 + quad * 8);
      fl[mi] = *(const f16x8*)(Kl + (size_t)(mi * 16 + l15) * 256 + kit * 32 + quad * 8);
    }
#pragma unroll
    for (int mi = 0; mi < 4; ++mi)
#pragma unroll
      for (int ni = 0; ni < 4; ++ni) {
        f32x4 d = D[mi * 4 + ni];
        d = __builtin_amdgcn_mfma_f32_16x16x32_f16(fh[mi], fh[ni], d, 0, 0, 0);
        d = __builtin_amdgcn_mfma_f32_16x16x32_f16(fh[mi], fl[ni], d, 0, 0, 0);
        d = __builtin_amdgcn_mfma_f32_16x16x32_f16(fl[mi], fh[ni], d, 0, 0, 0);
        D[mi * 4 + ni] = d;
      }
  }
#pragma unroll
  for (int mi = 0; mi < 4; ++mi)
#pragma unroll
    for (int ni = 0; ni < 4; ++ni)
#pragma unroll
      for (int r = 0; r < 4; ++r) {
        const int row = mi * 16 + quad * 4 + r;
        const float as_r = __shfl(aS, row);
        Gs[row][ni * 16 + l15] = as_r * D[mi * 4 + ni][r];
      }
  __syncthreads();

  float x[64];
#pragma unroll
  for (int t = 0; t < 64; ++t) x[t] = (t == lane) ? 1.f : 0.f;
#pragma unroll
  for (int t = 1; t < 64; ++t) {
    float acc = 0.f;
    const int n4 = t >> 2;
#pragma unroll
    for (int q4 = 0; q4 < 16; ++q4) {
      if (q4 >= n4) break;
      const float4 g = *(const float4*)&Gs[t][q4 * 4];
      acc += g.x * x[q4 * 4] + g.y * x[q4 * 4 + 1] + g.z * x[q4 * 4 + 2] + g.w * x[q4 * 4 + 3];
    }
#pragma unroll
    for (int tp = 0; tp < 4; ++tp) {
      const int ti = n4 * 4 + tp;
      if (ti >= t) break;
      acc += Gs[t][ti] * x[ti];
    }
    x[t] -= acc;
  }
  if (ck == 15) x[63] = 0.f;   // token L-1 is the query only: U row 63 = 0

  const size_t base = (size_t)wg * 4096;
#pragma unroll
  for (int t = 0; t < 64; ++t) {
    _Float16 h, l;
    fsplit(x[t], h, l);
    Tgh[base + t * 64 + lane] = h;
    Tgl[base + t * 64 + lane] = l;
  }
}

// ---------------- chunked WY delta-rule scan (v15).
// v15: 8-way column split (32 cols/WG) -> 1024 WGs = 4 blocks/CU (was 512
// = 2/CU, Occupancy 11.5%). Per-WG state halves (S regs 16->8, VGPR drops,
// LDS ~37KB). Cross-WG wave overlap hides the serial barrier chain. p==3
// panel barrier dropped (Sb[1]'s next write fenced by next chunk's BP0).
// Per-column math bit-identical to v14.
struct HT32 { _Float16 h[2304], l[2304]; };   // [32 j][72 t-stride] halves, 9216 B

__global__ __launch_bounds__(256) void scan_chunked(
    const _Float16* __restrict__ khs, const _Float16* __restrict__ kls,
    const _Float16* __restrict__ khe, const _Float16* __restrict__ kle,
    const float* __restrict__ ssqP, const float* __restrict__ wts,
    const _Float16* __restrict__ Tgh, const _Float16* __restrict__ Tgl,
    float* __restrict__ c_out)
{
  __shared__ HT32 Sb[2];                                    // S^T dbuf 18432 B
  __shared__ union { HT32 t; float cred[4][32]; } Yb;       // Y^T       9216 B
  __shared__ HT32 Ub;                                       // U^T       9216 B

  const int tid  = threadIdx.x;
  const int lane = tid & 63;
  const int wv   = tid >> 6;
  const int l15  = lane & 15;
  const int quad = lane >> 4;
  // XCD-affinity decode: all 8 col-slices of one (b,mat) share wg&7 -> one XCD
  const int wg   = blockIdx.x;
  const int x_   = wg & 7;
  const int q    = (wg >> 3) & 7;
  const int h_   = wg >> 6;            // 0..15
  const int grp  = x_ + (h_ << 3);     // 0..127, bijective
  const int b    = grp >> 1;
  const int mat  = grp & 1;
  const int j0   = q * 32;
  const _Float16* Kh = (mat ? khe : khs) + (size_t)b * (1024 * 256);
  const _Float16* Kl = (mat ? kle : kls) + (size_t)b * (1024 * 256);
  const _Float16* Tbh = Tgh + (size_t)((b * 2 + mat) * 16) * 4096;
  const _Float16* Tbl = Tgl + (size_t)((b * 2 + mat) * 16) * 4096;

  // S[p*2+nt]: rows p*64 + wv*16 + quad*4 + r ; cols nt*16 + l15 (WG-local j)
  f32x4 S[8];
#pragma unroll
  for (int i = 0; i < 8; ++i) S[i] = {0.f, 0.f, 0.f, 0.f};

  for (int ck = 0; ck < 16; ++ck) {
    const int tok0 = ck * 64;

    float myw[4], mya[4], kvv[4][2];
#pragma unroll
    for (int r = 0; r < 4; ++r) {
      const int t = tok0 + wv * 16 + quad * 4 + r;
      const float4 sq = *(const float4*)(ssqP + ((size_t)mat * kTok + (size_t)b * 1024 + t) * 4);
      const float w = mat ? wts[t] : 1.f;
      myw[r] = w;
      mya[r] = w / (sq.x + sq.y + sq.z + sq.w + 1e-6f);
#pragma unroll
      for (int nt = 0; nt < 2; ++nt) {
        const size_t go = (size_t)t * 256 + j0 + nt * 16 + l15;
        kvv[r][nt] = (float)Kh[go] + (float)Kl[go];
      }
    }
    f16x8 tah[2], tal[2];
#pragma unroll
    for (int kit = 0; kit < 2; ++kit) {
      const size_t to = (size_t)ck * 4096 + (size_t)(wv * 16 + l15) * 64 + kit * 32 + quad * 8;
      tah[kit] = *(const f16x8*)(Tbh + to);
      tal[kit] = *(const f16x8*)(Tbl + to);
    }
    const _Float16* arow_h = Kh + (size_t)(tok0 + wv * 16 + l15) * 256 + quad * 8;
    const _Float16* arow_l = Kl + (size_t)(tok0 + wv * 16 + l15) * 256 + quad * 8;
    f16x8 a0h = *(const f16x8*)(arow_h);
    f16x8 a1h = *(const f16x8*)(arow_h + 32);
    f16x8 a0l = *(const f16x8*)(arow_l);
    f16x8 a1l = *(const f16x8*)(arow_l + 32);

    // stage S^T panel 0 into Sb[0]
#pragma unroll
    for (int nt = 0; nt < 2; ++nt) {
      const f32x4 v = S[0 * 2 + nt];
      union { _Float16 h[4]; uint2 u; } qh, ql;
#pragma unroll
      for (int r = 0; r < 4; ++r) fsplit(v[r], qh.h[r], ql.h[r]);
      const int ix = (nt * 16 + l15) * 72 + wv * 16 + quad * 4;
      *(uint2*)&Sb[0].h[ix] = qh.u;
      *(uint2*)&Sb[0].l[ix] = ql.u;
    }
    __syncthreads();   // BP0

    // Q = K S^T over 4 d-panels
    f32x4 Qa[2];
#pragma unroll
    for (int i = 0; i < 2; ++i) Qa[i] = {0.f, 0.f, 0.f, 0.f};
#pragma unroll
    for (int p = 0; p < 4; ++p) {
      const int cur = p & 1;
      f16x8 n0h, n1h, n0l, n1l;
      if (p < 3) {
        n0h = *(const f16x8*)(arow_h + (p + 1) * 64);
        n1h = *(const f16x8*)(arow_h + (p + 1) * 64 + 32);
        n0l = *(const f16x8*)(arow_l + (p + 1) * 64);
        n1l = *(const f16x8*)(arow_l + (p + 1) * 64 + 32);
#pragma unroll
        for (int nt = 0; nt < 2; ++nt) {
          const f32x4 v = S[(p + 1) * 2 + nt];
          union { _Float16 h[4]; uint2 u; } sh2, sl2;
#pragma unroll
          for (int r = 0; r < 4; ++r) fsplit(v[r], sh2.h[r], sl2.h[r]);
          const int ix = (nt * 16 + l15) * 72 + wv * 16 + quad * 4;
          *(uint2*)&Sb[1 - cur].h[ix] = sh2.u;
          *(uint2*)&Sb[1 - cur].l[ix] = sl2.u;
        }
      }
#pragma unroll
      for (int kit = 0; kit < 2; ++kit) {
        const f16x8 ah = kit ? a1h : a0h;
        const f16x8 al = kit ? a1l : a0l;
#pragma unroll
        for (int nt = 0; nt < 2; ++nt) {
          const int ix = (nt * 16 + l15) * 72 + kit * 32 + quad * 8;
          const f16x8 bh = *(const f16x8*)&Sb[cur].h[ix];
          const f16x8 bl = *(const f16x8*)&Sb[cur].l[ix];
          Qa[nt] = __builtin_amdgcn_mfma_f32_16x16x32_f16(ah, bh, Qa[nt], 0, 0, 0);
          Qa[nt] = __builtin_amdgcn_mfma_f32_16x16x32_f16(ah, bl, Qa[nt], 0, 0, 0);
          Qa[nt] = __builtin_amdgcn_mfma_f32_16x16x32_f16(al, bh, Qa[nt], 0, 0, 0);
        }
      }
      if (p < 3) {
        a0h = n0h; a1h = n1h; a0l = n0l; a1l = n1l;
        __syncthreads();   // dbuf WAR (p==3 barrier dropped: next write to
      }                    //  Sb happens after next chunk's BP0)
    }

    // Y = W*Kv - A*Q, stage Y^T[j][t]
#pragma unroll
    for (int nt = 0; nt < 2; ++nt) {
      union { _Float16 h[4]; uint2 u; } yh, yl;
#pragma unroll
      for (int r = 0; r < 4; ++r) {
        const float y = myw[r] * kvv[r][nt] - mya[r] * Qa[nt][r];
        fsplit(y, yh.h[r], yl.h[r]);
      }
      const int ix = (nt * 16 + l15) * 72 + wv * 16 + quad * 4;
      *(uint2*)&Yb.t.h[ix] = yh.u;
      *(uint2*)&Yb.t.l[ix] = yl.u;
    }
    __syncthreads();   // BY

    // U = T*Y
    f32x4 Ua[2];
#pragma unroll
    for (int i = 0; i < 2; ++i) Ua[i] = {0.f, 0.f, 0.f, 0.f};
#pragma unroll
    for (int kit = 0; kit < 2; ++kit)
#pragma unroll
      for (int nt = 0; nt < 2; ++nt) {
        const int ix = (nt * 16 + l15) * 72 + kit * 32 + quad * 8;
        const f16x8 yh = *(const f16x8*)&Yb.t.h[ix];
        const f16x8 yl = *(const f16x8*)&Yb.t.l[ix];
        Ua[nt] = __builtin_amdgcn_mfma_f32_16x16x32_f16(tah[kit], yh, Ua[nt], 0, 0, 0);
        Ua[nt] = __builtin_amdgcn_mfma_f32_16x16x32_f16(tah[kit], yl, Ua[nt], 0, 0, 0);
        Ua[nt] = __builtin_amdgcn_mfma_f32_16x16x32_f16(tal[kit], yh, Ua[nt], 0, 0, 0);
      }
    // stage U^T[j][t]
#pragma unroll
    for (int nt = 0; nt < 2; ++nt) {
      union { _Float16 h[4]; uint2 u; } uh, ul;
#pragma unroll
      for (int r = 0; r < 4; ++r) fsplit(Ua[nt][r], uh.h[r], ul.h[r]);
      const int ix = (nt * 16 + l15) * 72 + wv * 16 + quad * 4;
      *(uint2*)&Ub.h[ix] = uh.u;
      *(uint2*)&Ub.l[ix] = ul.u;
    }
    __syncthreads();   // BU

    // S += K^T U (A-frags = L2-hot scalar global loads; barrier-free)
#pragma unroll
    for (int p = 0; p < 4; ++p) {
      union { _Float16 e[8]; f16x8 v; } kah[2], kal[2];
#pragma unroll
      for (int kit = 0; kit < 2; ++kit)
#pragma unroll
        for (int jj = 0; jj < 8; ++jj) {
          const size_t gko = (size_t)(tok0 + kit * 32 + quad * 8 + jj) * 256
                           + p * 64 + wv * 16 + l15;
          kah[kit].e[jj] = Kh[gko];
          kal[kit].e[jj] = Kl[gko];
        }
#pragma unroll
      for (int kit = 0; kit < 2; ++kit)
#pragma unroll
        for (int nt = 0; nt < 2; ++nt) {
          const int ix = (nt * 16 + l15) * 72 + kit * 32 + quad * 8;
          const f16x8 ubh = *(const f16x8*)&Ub.h[ix];
          const f16x8 ubl = *(const f16x8*)&Ub.l[ix];
          f32x4 s = S[p * 2 + nt];
          s = __builtin_amdgcn_mfma_f32_16x16x32_f16(kah[kit].v, ubh, s, 0, 0, 0);
          s = __builtin_amdgcn_mfma_f32_16x16x32_f16(kah[kit].v, ubl, s, 0, 0, 0);
          s = __builtin_amdgcn_mfma_f32_16x16x32_f16(kal[kit].v, ubh, s, 0, 0, 0);
          S[p * 2 + nt] = s;
        }
    }
    // next chunk's BP0 orders Ub WAR and Sb reuse
  }

  // readout: c[col] = sum_rows S[row][col] * k_last[row]
  float part[2] = {0.f, 0.f};
  const size_t lastoff = (size_t)(kL - 1) * 256;
#pragma unroll
  for (int p = 0; p < 4; ++p) {
    float klr[4];
#pragma unroll
    for (int r = 0; r < 4; ++r) {
      const int row = p * 64 + wv * 16 + quad * 4 + r;
      klr[r] = (float)Kh[lastoff + row] + (float)Kl[lastoff + row];
    }
#pragma unroll
    for (int nt = 0; nt < 2; ++nt)
#pragma unroll
      for (int r = 0; r < 4; ++r) part[nt] += S[p * 2 + nt][r] * klr[r];
  }
#pragma unroll
  for (int nt = 0; nt < 2; ++nt) {
    part[nt] += __shfl_xor(part[nt], 16);
    part[nt] += __shfl_xor(part[nt], 32);
  }
  __syncthreads();   // all prior LDS reads done before cred aliases Yb
  if (lane < 16) {
#pragma unroll
    for (int nt = 0; nt < 2; ++nt) Yb.cred[wv][nt * 16 + l15] = part[nt];
  }
  __syncthreads();
  if (tid < 32) {
    const float c = Yb.cred[0][tid] + Yb.cred[1][tid] + Yb.cred[2][tid] + Yb.cred[3][tid];
    c_out[(size_t)b * 512 + mat * 256 + j0 + tid] = c;
  }
}

// ---------------- output GEMM: (64 x 512) @ (512 x 32000) + out_b -> fp32
__global__ __launch_bounds__(256) void out_gemm(
    const float* __restrict__ A, const float* __restrict__ Bm,
    const float* __restrict__ bias, float* __restrict__ C)
{
  __shared__ float As[16][64];
  __shared__ float Bs[16][128];
  const int tid = threadIdx.x;
  const int bn0 = blockIdx.x * 128;
  const int tm = tid >> 4, tn = tid & 15;
  float acc[4][8];
#pragma unroll
  for (int i = 0; i < 4; ++i)
#pragma unroll
    for (int j = 0; j < 8; ++j) acc[i][j] = 0.f;

  const int am  = tid & 63;
  const int ak  = (tid >> 6) * 4;
  const int bkr = tid >> 5;
  const int bcg = (tid & 31) * 4;

  for (int k0 = 0; k0 < kH; k0 += 16) {
    const float4 a0 = *(const float4*)(A + (size_t)am * kH + k0 + ak);
    const float4 b0 = *(const float4*)(Bm + (size_t)(k0 + bkr) * kV + bn0 + bcg);
    const float4 b1 = *(const float4*)(Bm + (size_t)(k0 + bkr + 8) * kV + bn0 + bcg);
    __syncthreads();
    As[ak + 0][am] = a0.x; As[ak + 1][am] = a0.y;
    As[ak + 2][am] = a0.z; As[ak + 3][am] = a0.w;
    *(float4*)&Bs[bkr][bcg]     = b0;
    *(float4*)&Bs[bkr + 8][bcg] = b1;
    __syncthreads();
#pragma unroll
    for (int kk = 0; kk < 16; ++kk) {
      const float4 aA = *(const float4*)&As[kk][tm * 4];
      const float4 bA = *(const float4*)&Bs[kk][tn * 4];
      const float4 bB = *(const float4*)&Bs[kk][64 + tn * 4];
      const float av[4] = {aA.x, aA.y, aA.z, aA.w};
      const float bv[8] = {bA.x, bA.y, bA.z, bA.w, bB.x, bB.y, bB.z, bB.w};
#pragma unroll
      for (int i = 0; i < 4; ++i)
#pragma unroll
        for (int j = 0; j < 8; ++j) acc[i][j] += av[i] * bv[j];
    }
  }

#pragma unroll
  for (int i = 0; i < 4; ++i) {
    const int row = tm * 4 + i;
#pragma unroll
    for (int hh = 0; hh < 2; ++hh) {
      const int n0 = bn0 + tn * 4 + hh * 64;
      const float4 bb = *(const float4*)(bias + n0);
      float4 o;
      o.x = acc[i][hh * 4 + 0] + bb.x;
      o.y = acc[i][hh * 4 + 1] + bb.y;
      o.z = acc[i][hh * 4 + 2] + bb.z;
      o.w = acc[i][hh * 4 + 3] + bb.w;
      *(float4*)(C + (size_t)row * kV + n0) = o;
    }
  }
}

}  // namespace

extern "C" void kernel_launch(void* const* d_in, const int* in_sizes, int n_in,
                              void* d_out, int out_size, void* d_ws, size_t ws_size,
                              hipStream_t stream)
{
  const int*   seq     = (const int*)  d_in[0];
  const float* embed   = (const float*)d_in[1];
  const float* w1      = (const float*)d_in[2];
  const float* b1      = (const float*)d_in[3];
  const float* w2      = (const float*)d_in[4];
  const float* b2      = (const float*)d_in[5];
  const float* ln_g    = (const float*)d_in[6];
  const float* ln_b    = (const float*)d_in[7];
  const float* sem_w   = (const float*)d_in[8];
  const float* sem_b   = (const float*)d_in[9];
  const float* epi_w   = (const float*)d_in[10];
  const float* epi_b   = (const float*)d_in[11];
  const float* out_w   = (const float*)d_in[12];
  const float* out_b   = (const float*)d_in[13];
  const float* pos_emb = (const float*)d_in[14];
  const float* pos_w   = (const float*)d_in[15];
  const float* pos_b   = (const float*)d_in[16];
  float* out = (float*)d_out;

  const int chunkN = (ws_size >= (size_t)240500000) ? 16384 : 8192;
  const int nch    = kTok / chunkN;
  const int nyb    = chunkN / 1024;   // Ny/8 = (chunkN/128)/8
  const int tband  = chunkN / 8;

  char* p = (char*)d_ws;
  _Float16* w1th = (_Float16*)p; p += (size_t)1024 * 512 * 2;
  _Float16* w1tl = (_Float16*)p; p += (size_t)1024 * 512 * 2;   // unused (PROD=1)
  _Float16* w2th = (_Float16*)p; p += (size_t)512 * 1024 * 2;
  _Float16* w2tl = (_Float16*)p; p += (size_t)512 * 1024 * 2;   // unused (PROD=1)
  _Float16* wseh = (_Float16*)p; p += (size_t)512 * 512 * 2;
  _Float16* wsel = (_Float16*)p; p += (size_t)512 * 512 * 2;
  _Float16* t1h  = (_Float16*)p; p += (size_t)chunkN * 1024 * 2;
  _Float16* t1l  = (_Float16*)p; p += (size_t)chunkN * 1024 * 2;   // (spare; T-lo alias)
  float*    x    = (float*)p;    p += (size_t)chunkN * kH * 4;
  _Float16* khs  = (_Float16*)p; p += (size_t)kTok * kHalf * 2;   // K hi/lo fp16
  _Float16* kls  = (_Float16*)p; p += (size_t)kTok * kHalf * 2;
  _Float16* khe  = (_Float16*)p; p += (size_t)kTok * kHalf * 2;
  _Float16* kle  = (_Float16*)p; p += (size_t)kTok * kHalf * 2;
  float*    wts  = (float*)p;    p += (size_t)kL * 4;
  float*    cout_= (float*)p;    p += (size_t)kB * 512 * 4;
  float*    ssqp = (float*)p;    p += (size_t)2 * kTok * 4 * 4;   // [mat][tok][4] partials
  _Float16* hh   = t1h;          // alias: t1 dead once x is written
  _Float16* Tgh = t1h;           // T aliases t1 (dead after chunk loop)
  _Float16* Tgl = t1l;

  pos_kernel<<<dim3((kL + 255) / 256), dim3(256), 0, stream>>>(pos_emb, pos_w, pos_b, wts);
  transpose_split<<<dim3(1024 * 512 / 256), dim3(256), 0, stream>>>(w1, w1th, w1tl, 1024, 9);
  transpose_split<<<dim3(512 * 1024 / 256), dim3(256), 0, stream>>>(w2, w2th, w2tl, 512, 10);
  transpose_split<<<dim3(256 * 512 / 256), dim3(256), 0, stream>>>(sem_w, wseh, wsel, 256, 9);
  transpose_split<<<dim3(256 * 512 / 256), dim3(256), 0, stream>>>(
      epi_w, wseh + (size_t)256 * 512, wsel + (size_t)256 * 512, 256, 9);

  for (int c = 0; c < nch; ++c) {
    const int tok0 = c * chunkN;
    hgemm<0, 1><<<dim3((1024 / 128) * (chunkN / 128)), dim3(256), 0, stream>>>(
        seq, embed, nullptr, w1th, nullptr, b1, nullptr,
        nullptr, t1h, nullptr, nullptr, nullptr, 512, 1024, tok0, nyb);
    hgemm<1, 1><<<dim3((512 / 128) * (chunkN / 128)), dim3(256), 0, stream>>>(
        seq, embed, t1h, w2th, nullptr, b2, nullptr,
        x, nullptr, nullptr, nullptr, nullptr, 1024, 512, tok0, nyb);
    ln_split<<<dim3(chunkN / 4), dim3(256), 0, stream>>>(x, ln_g, ln_b, hh, tband);
    hgemm<2, 2><<<dim3((512 / 128) * (chunkN / 128)), dim3(256), 0, stream>>>(
        seq, embed, hh, wseh, wsel, sem_b, epi_b,
        ssqp, kls, kle, (float*)khs, (float*)khe,
        512, 512, tok0, nyb);
  }

  tinv_kernel<<<dim3(2048), dim3(64), 0, stream>>>(
      khs, kls, khe, kle, ssqp, wts, Tgh, Tgl);
  scan_chunked<<<dim3(1024), dim3(256), 0, stream>>>(
      khs, kls, khe, kle, ssqp, wts, Tgh, Tgl, cout_);
  out_gemm<<<dim3(kV / 128), dim3(256), 0, stream>>>(cout_, out_w, out_b, out);

  (void)in_sizes; (void)n_in; (void)out_size;
}

// Round 12
// 888.285 us; speedup vs baseline: 1.1168x; 1.1168x over previous
//
#include <hip/hip_runtime.h>
#include <hip/hip_bf16.h>
#include <math.h>

namespace {

constexpr int kH     = 512;
constexpr int kL     = 1024;
constexpr int kB     = 64;
constexpr int kHalf  = 256;
constexpr int kV     = 32000;
constexpr int kTok   = kB * kL;     // 65536

using f32x4 = __attribute__((ext_vector_type(4))) float;
using f16x8 = __attribute__((ext_vector_type(8))) _Float16;

__device__ inline void fsplit(float v, _Float16& h, _Float16& l) {
  h = (_Float16)v;
  l = (_Float16)(v - (float)h);
}

// async 16B global->LDS (gfx950). dst must be wave-uniform base; lane l
// receives bytes [l*16, l*16+16). The GLOBAL source address is per-lane.
typedef __attribute__((address_space(3))) void lds_vp;
typedef const __attribute__((address_space(1))) void glb_vp;
__device__ inline void gload16(const void* g, void* l) {
  __builtin_amdgcn_global_load_lds((glb_vp*)g, (lds_vp*)l, 16, 0, 0);
}

// Row-PAIR swizzled half-tile index for [128][32]-half tiles stored flat.
__device__ inline int hswz(int row, int col) {
  const int sr = row >> 1;
  const int g  = ((row & 1) << 2) | (col >> 3);
  return sr * 64 + (((g ^ (sr & 7)) << 3) | (col & 7));
}

// ---------------- positional weights
__global__ void pos_kernel(const float* __restrict__ pos_emb,
                           const float* __restrict__ pos_w,
                           const float* __restrict__ pos_b,
                           float* __restrict__ wts)
{
  int t = blockIdx.x * blockDim.x + threadIdx.x;
  if (t >= kL) return;
  float z = pos_b[0];
#pragma unroll
  for (int p = 0; p < 16; ++p) z += pos_emb[t * 16 + p] * pos_w[p];
  wts[t] = 1.f / (1.f + expf(-z));
}

// ---------------- embed fp32 -> fp16 (one-time; enables async A-gather)
__global__ __launch_bounds__(256) void emb_half(
    const float* __restrict__ e, _Float16* __restrict__ o)
{
  const size_t i = ((size_t)blockIdx.x * 256 + threadIdx.x) * 8;
  const float4 v0 = *(const float4*)(e + i);
  const float4 v1 = *(const float4*)(e + i + 4);
  union { _Float16 h[8]; uint4 u; } ph;
  ph.h[0] = (_Float16)v0.x; ph.h[1] = (_Float16)v0.y;
  ph.h[2] = (_Float16)v0.z; ph.h[3] = (_Float16)v0.w;
  ph.h[4] = (_Float16)v1.x; ph.h[5] = (_Float16)v1.y;
  ph.h[6] = (_Float16)v1.z; ph.h[7] = (_Float16)v1.w;
  *(uint4*)(o + i) = ph.u;
}

// ---------------- transpose + hi/lo fp16 split: W[K][N] fp32 -> Th/Tl[N][K]
__global__ __launch_bounds__(256) void transpose_split(
    const float* __restrict__ W, _Float16* __restrict__ Th,
    _Float16* __restrict__ Tl, int N, int kshift)
{
  const int idx = blockIdx.x * 256 + threadIdx.x;
  const int K = 1 << kshift;
  const int k = idx & (K - 1);
  const int n = idx >> kshift;
  const float w = W[(size_t)k * N + n];
  const _Float16 h = (_Float16)w;
  Th[idx] = h;
  Tl[idx] = (_Float16)(w - (float)h);
}

// ---------------- mixed-precision MFMA GEMM: C = A(fp16) @ B[N,K]^T
// XCD-banded 1D grid + 2-phase async dbuf pipeline (v14). AFP16=1 (EPI==0):
// A rows gathered from fp16 embed via per-lane-source global_load_lds.
template <int EPI, int PROD, int AFP16 = 0>
__global__ __launch_bounds__(256) void hgemm(
    const int* __restrict__ seq, const float* __restrict__ embed,
    const _Float16* __restrict__ Ah,
    const _Float16* __restrict__ Bh, const _Float16* __restrict__ Bl,
    const float* __restrict__ bias, const float* __restrict__ bias2,
    float* __restrict__ Xout, _Float16* __restrict__ Oh, _Float16* __restrict__ Ol,
    float* __restrict__ ks, float* __restrict__ ke,
    int K, int N, int tok0c, int nyb)   // nyb = Ny/8 (token-band rows per XCD)
{
  constexpr int TILES = 1 + PROD;              // A, Bh (, Bl)
  __shared__ __align__(16) _Float16 lds[2 * TILES * 4096];  // dbuf
  const int tid  = threadIdx.x;
  const int lane = tid & 63;
  const int wv   = tid >> 6;
  const int wm   = (wv >> 1) * 64;
  const int wn   = (wv & 1) * 64;
  // XCD-banded decode (bijective for Ny%8==0)
  const int idb  = blockIdx.x;
  const int xcd  = idb & 7;
  const int j    = idb >> 3;
  const int x_   = j / nyb;
  const int yb   = j - x_ * nyb;
  const int bm0  = (xcd * nyb + yb) * 128;
  const int bn0  = x_ * 128;

  f32x4 acc[4][4];
#pragma unroll
  for (int i = 0; i < 4; ++i)
#pragma unroll
    for (int j2 = 0; j2 < 4; ++j2) acc[i][j2] = {0.f, 0.f, 0.f, 0.f};

  // async staging geometry: lane l writes phys 16B granule (super-row l>>3,
  // slot l&7); inverse-swizzled global source:
  const int sl   = lane >> 3;                 // local super-row 0..7
  const int gg   = (lane & 7) ^ sl;           // logical granule
  const int trow = wv * 16 + sl * 2 + (gg >> 2);
  const int tcol = (gg & 3) * 8;              // halves within the 32-half k-step
  const size_t brow0 = (size_t)(bn0 + trow) * K + tcol;
  const size_t brow1 = (size_t)(bn0 + trow + 64) * K + tcol;
  size_t arow0 = 0, arow1 = 0;
  const float* gAe = nullptr;
  if constexpr (EPI == 0) {
    if constexpr (AFP16) {   // per-lane gathered fp16 embed rows (async path)
      const int t0r = seq[tok0c + bm0 + trow];
      const int t1r = seq[tok0c + bm0 + trow + 64];
      arow0 = (size_t)t0r * kH + tcol;
      arow1 = (size_t)t1r * kH + tcol;
    } else {
      const int sr = tid >> 1;
      const int tokrow = seq[tok0c + bm0 + sr];
      gAe = embed + (size_t)tokrow * kH + ((tid & 1) << 4);
    }
  } else {
    arow0 = (size_t)(bm0 + trow) * K + tcol;
    arow1 = (size_t)(bm0 + trow + 64) * K + tcol;
  }
  // wave-uniform LDS bases (halves)
  const int lb0 = wv * 512;
  const int lb1 = 2048 + wv * 512;

  const int lrow = lane & 15;
  const int lk   = (lane >> 4) * 8;
  const int NT   = K >> 5;

  for (int t = 0; t <= NT; ++t) {
    const int kc = t << 5;
    float4 a0, a1, a2, a3;
    if (t < NT) {                       // issue tile-t loads (latency hides
      if constexpr (EPI == 0 && !AFP16) {
        a0 = *(const float4*)(gAe + kc);
        a1 = *(const float4*)(gAe + kc + 4);
        a2 = *(const float4*)(gAe + kc + 8);
        a3 = *(const float4*)(gAe + kc + 12);
      }
      const int bo = (t & 1) * TILES * 4096;
      if constexpr (EPI != 0 || AFP16) {
        gload16(Ah + arow0 + kc, &lds[bo + lb0]);
        gload16(Ah + arow1 + kc, &lds[bo + lb1]);
      }
      gload16(Bh + brow0 + kc, &lds[bo + 4096 + lb0]);
      gload16(Bh + brow1 + kc, &lds[bo + 4096 + lb1]);
      if constexpr (PROD == 2) {
        gload16(Bl + brow0 + kc, &lds[bo + 8192 + lb0]);
        gload16(Bl + brow1 + kc, &lds[bo + 8192 + lb1]);
      }
    }
    if (t > 0) {                        // compute tile t-1
      const int po = ((t - 1) & 1) * TILES * 4096;
      f16x8 fBh[4], fBl[4];
#pragma unroll
      for (int ni = 0; ni < 4; ++ni) {
        fBh[ni] = *(const f16x8*)&lds[po + 4096 + hswz(wn + ni * 16 + lrow, lk)];
        if constexpr (PROD == 2)
          fBl[ni] = *(const f16x8*)&lds[po + 8192 + hswz(wn + ni * 16 + lrow, lk)];
      }
#pragma unroll
      for (int mi = 0; mi < 4; ++mi) {
        const f16x8 ah = *(const f16x8*)&lds[po + hswz(wm + mi * 16 + lrow, lk)];
#pragma unroll
        for (int ni = 0; ni < 4; ++ni) {
          acc[mi][ni] = __builtin_amdgcn_mfma_f32_16x16x32_f16(ah, fBh[ni], acc[mi][ni], 0, 0, 0);
          if constexpr (PROD == 2)
            acc[mi][ni] = __builtin_amdgcn_mfma_f32_16x16x32_f16(ah, fBl[ni], acc[mi][ni], 0, 0, 0);
        }
      }
    }
    if (t < NT) {
      if constexpr (EPI == 0 && !AFP16) {   // manual A stage (embed gather)
        const float vv[16] = {a0.x,a0.y,a0.z,a0.w, a1.x,a1.y,a1.z,a1.w,
                              a2.x,a2.y,a2.z,a2.w, a3.x,a3.y,a3.z,a3.w};
        union { _Float16 h[16]; uint4 u[2]; } ph;
#pragma unroll
        for (int i = 0; i < 16; ++i) ph.h[i] = (_Float16)vv[i];
        const int sr = tid >> 1;
        const int sc = (tid & 1) << 4;
        const int bo = (t & 1) * TILES * 4096;
        *(uint4*)&lds[bo + hswz(sr, sc)]     = ph.u[0];
        *(uint4*)&lds[bo + hswz(sr, sc + 8)] = ph.u[1];
      }
    }
    __syncthreads();   // drains tile-t vmcnt (hidden under tile t-1 MFMA) + lgkm
  }

  const int erow0 = (lane >> 4) * 4;
  if constexpr (EPI == 0) {
#pragma unroll
    for (int mi = 0; mi < 4; ++mi)
#pragma unroll
      for (int ni = 0; ni < 4; ++ni) {
        const int gn = bn0 + wn + ni * 16 + (lane & 15);
        const float bv = bias[gn];
#pragma unroll
        for (int r = 0; r < 4; ++r) {
          const int gm = bm0 + wm + mi * 16 + erow0 + r;
          float v = fmaxf(acc[mi][ni][r] + bv, 0.f);
          Oh[(size_t)gm * N + gn] = (_Float16)v;
        }
      }
  } else if constexpr (EPI == 1) {
#pragma unroll
    for (int mi = 0; mi < 4; ++mi)
#pragma unroll
      for (int r = 0; r < 4; ++r) {
        const int gm = bm0 + wm + mi * 16 + erow0 + r;
        const int tok = seq[tok0c + gm];
        const float* er = embed + (size_t)tok * kH;
#pragma unroll
        for (int ni = 0; ni < 4; ++ni) {
          const int gn = bn0 + wn + ni * 16 + (lane & 15);
          Xout[(size_t)gm * N + gn] = acc[mi][ni][r] + bias[gn] + er[gn];
        }
      }
  } else {
    // EPI==2: write K as fp16 hi/lo pairs + per-quarter ssq partials (Xout).
    _Float16* kh_s = (_Float16*)ks;
    _Float16* kh_e = (_Float16*)ke;
    float s2[4][4];
#pragma unroll
    for (int mi = 0; mi < 4; ++mi)
#pragma unroll
      for (int r = 0; r < 4; ++r) s2[mi][r] = 0.f;
#pragma unroll
    for (int mi = 0; mi < 4; ++mi)
#pragma unroll
      for (int ni = 0; ni < 4; ++ni) {
        const int gn = bn0 + wn + ni * 16 + (lane & 15);
        const float bv = (gn < 256) ? bias[gn] : bias2[gn - 256];
        _Float16* Dh = (gn < 256) ? kh_s : kh_e;
        _Float16* Dl = (gn < 256) ? Oh : Ol;
        const int col = gn & 255;
#pragma unroll
        for (int r = 0; r < 4; ++r) {
          const int gm = bm0 + wm + mi * 16 + erow0 + r;
          const float v = acc[mi][ni][r] + bv;
          s2[mi][r] += v * v;
          _Float16 h, l;
          fsplit(v, h, l);
          Dh[(size_t)(tok0c + gm) * 256 + col] = h;
          Dl[(size_t)(tok0c + gm) * 256 + col] = l;
        }
      }
    // deterministic per-quarter partial sums: ssqPart[mat][tok][half*2 + (wv&1)]
    const int matq  = bn0 >> 8;
    const int halfq = (bn0 >> 7) & 1;
#pragma unroll
    for (int mi = 0; mi < 4; ++mi)
#pragma unroll
      for (int r = 0; r < 4; ++r) {
        float s2v = s2[mi][r];
        s2v += __shfl_xor(s2v, 1);
        s2v += __shfl_xor(s2v, 2);
        s2v += __shfl_xor(s2v, 4);
        s2v += __shfl_xor(s2v, 8);
        if ((lane & 15) == 0) {
          const int gm = bm0 + wm + mi * 16 + erow0 + r;
          Xout[((size_t)matq * kTok + (size_t)(tok0c + gm)) * 4 + halfq * 2 + (wv & 1)] = s2v;
        }
      }
  }
}

// ---------------- LayerNorm: x fp32 -> fp16 (hi only), XCD-banded tokens
__global__ __launch_bounds__(256) void ln_split(
    const float* __restrict__ x, const float* __restrict__ g,
    const float* __restrict__ bta, _Float16* __restrict__ hh, int tband)
{
  const int wid  = threadIdx.x >> 6;
  const int lane = threadIdx.x & 63;
  const int id   = blockIdx.x;
  const int ltok = (id & 7) * tband + (id >> 3) * 4 + wid;
  const float* xp = x + (size_t)ltok * kH;
  const float4 v0 = *(const float4*)(xp + lane * 8);
  const float4 v1 = *(const float4*)(xp + lane * 8 + 4);
  float s  = v0.x + v0.y + v0.z + v0.w + v1.x + v1.y + v1.z + v1.w;
  float ss = v0.x * v0.x + v0.y * v0.y + v0.z * v0.z + v0.w * v0.w +
             v1.x * v1.x + v1.y * v1.y + v1.z * v1.z + v1.w * v1.w;
#pragma unroll
  for (int m = 1; m < 64; m <<= 1) { s += __shfl_xor(s, m); ss += __shfl_xor(ss, m); }
  const float mu  = s * (1.f / kH);
  const float var = ss * (1.f / kH) - mu * mu;
  const float rs  = 1.f / sqrtf(var + 1e-5f);
  const float4 g0 = *(const float4*)(g + lane * 8);
  const float4 g1 = *(const float4*)(g + lane * 8 + 4);
  const float4 b0 = *(const float4*)(bta + lane * 8);
  const float4 b1 = *(const float4*)(bta + lane * 8 + 4);
  const float vv[8] = {v0.x, v0.y, v0.z, v0.w, v1.x, v1.y, v1.z, v1.w};
  const float gg[8] = {g0.x, g0.y, g0.z, g0.w, g1.x, g1.y, g1.z, g1.w};
  const float bb[8] = {b0.x, b0.y, b0.z, b0.w, b1.x, b1.y, b1.z, b1.w};
  union { _Float16 h[8]; uint4 u; } ph;
#pragma unroll
  for (int i = 0; i < 8; ++i) {
    const float o = (vv[i] - mu) * rs * gg[i] + bb[i];
    ph.h[i] = (_Float16)o;
  }
  *(uint4*)(hh + (size_t)ltok * kH + lane * 8) = ph.u;
}

// ---------------- T precompute: T = (I + diag(aS)*tril_strict(K K^T))^{-1}
__global__ __launch_bounds__(64) void tinv_kernel(
    const _Float16* __restrict__ khs, const _Float16* __restrict__ kls,
    const _Float16* __restrict__ khe, const _Float16* __restrict__ kle,
    const float* __restrict__ ssqP, const float* __restrict__ wts,
    _Float16* __restrict__ Tgh, _Float16* __restrict__ Tgl)
{
  __shared__ float Gs[64][68];
  const int lane = threadIdx.x;
  const int l15  = lane & 15;
  const int quad = lane >> 4;
  const int wg   = blockIdx.x;
  const int ck   = wg & 15;
  const int mat  = (wg >> 4) & 1;
  const int b    = wg >> 5;
  const _Float16* Kh = (mat ? khe : khs) + (size_t)b * (1024 * 256) + (size_t)ck * 64 * 256;
  const _Float16* Kl = (mat ? kle : kls) + (size_t)b * (1024 * 256) + (size_t)ck * 64 * 256;

  const float4 sq = *(const float4*)(ssqP + ((size_t)mat * kTok + (size_t)b * 1024 + ck * 64 + lane) * 4);
  const float w  = mat ? wts[ck * 64 + lane] : 1.f;
  const float aS = w / (sq.x + sq.y + sq.z + sq.w + 1e-6f);

  // G = K K^T via split-fp16 MFMA
  f32x4 D[16];
#pragma unroll
  for (int i = 0; i < 16; ++i) D[i] = {0.f, 0.f, 0.f, 0.f};
#pragma unroll
  for (int kit = 0; kit < 8; ++kit) {
    f16x8 fh[4], fl[4];
#pragma unroll
    for (int mi = 0; mi < 4; ++mi) {
      fh[mi] = *(const f16x8*)(Kh + (size_t)(mi * 16 + l15) * 256 + kit * 32 + quad * 8);
      fl[mi] = *(const f16x8*)(Kl + (size_t)(mi * 16 + l15) * 256 + kit * 32 + quad * 8);
    }
#pragma unroll
    for (int mi = 0; mi < 4; ++mi)
#pragma unroll
      for (int ni = 0; ni < 4; ++ni) {
        f32x4 d = D[mi * 4 + ni];
        d = __builtin_amdgcn_mfma_f32_16x16x32_f16(fh[mi], fh[ni], d, 0, 0, 0);
        d = __builtin_amdgcn_mfma_f32_16x16x32_f16(fh[mi], fl[ni], d, 0, 0, 0);
        d = __builtin_amdgcn_mfma_f32_16x16x32_f16(fl[mi], fh[ni], d, 0, 0, 0);
        D[mi * 4 + ni] = d;
      }
  }
#pragma unroll
  for (int mi = 0; mi < 4; ++mi)
#pragma unroll
    for (int ni = 0; ni < 4; ++ni)
#pragma unroll
      for (int r = 0; r < 4; ++r) {
        const int row = mi * 16 + quad * 4 + r;
        const float as_r = __shfl(aS, row);
        Gs[row][ni * 16 + l15] = as_r * D[mi * 4 + ni][r];
      }
  __syncthreads();

  float x[64];
#pragma unroll
  for (int t = 0; t < 64; ++t) x[t] = (t == lane) ? 1.f : 0.f;
#pragma unroll
  for (int t = 1; t < 64; ++t) {
    float acc = 0.f;
    const int n4 = t >> 2;
#pragma unroll
    for (int q4 = 0; q4 < 16; ++q4) {
      if (q4 >= n4) break;
      const float4 g = *(const float4*)&Gs[t][q4 * 4];
      acc += g.x * x[q4 * 4] + g.y * x[q4 * 4 + 1] + g.z * x[q4 * 4 + 2] + g.w * x[q4 * 4 + 3];
    }
#pragma unroll
    for (int tp = 0; tp < 4; ++tp) {
      const int ti = n4 * 4 + tp;
      if (ti >= t) break;
      acc += Gs[t][ti] * x[ti];
    }
    x[t] -= acc;
  }
  if (ck == 15) x[63] = 0.f;   // token L-1 is the query only: U row 63 = 0

  const size_t base = (size_t)wg * 4096;
#pragma unroll
  for (int t = 0; t < 64; ++t) {
    _Float16 h, l;
    fsplit(x[t], h, l);
    Tgh[base + t * 64 + lane] = h;
    Tgl[base + t * 64 + lane] = l;
  }
}

// ---------------- chunked WY delta-rule scan (v14 structure — reverted from
// v15's 8-way split which REGRESSED: per-WG fixed overhead doubled while
// work halved; occupancy stayed 11.5% because the kernel is stall-bound).
// Only change vs v14: p==3 panel barrier dropped (Sb[1] readers fenced by
// BY/BU/next-BP0 before its next write).
struct HTile { _Float16 h[4608], l[4608]; };   // [64][72] halves hi/lo, 18432 B

__global__ __launch_bounds__(256) void scan_chunked(
    const _Float16* __restrict__ khs, const _Float16* __restrict__ kls,
    const _Float16* __restrict__ khe, const _Float16* __restrict__ kle,
    const float* __restrict__ ssqP, const float* __restrict__ wts,
    const _Float16* __restrict__ Tgh, const _Float16* __restrict__ Tgl,
    float* __restrict__ c_out)
{
  __shared__ HTile Sb[2];                                   // S^T dbuf 36864 B
  __shared__ union { HTile t; float cred[4][64]; } Yb;      // Y^T      18432 B
  __shared__ HTile Ub;                                      // U^T      18432 B

  const int tid  = threadIdx.x;
  const int lane = tid & 63;
  const int wv   = tid >> 6;
  const int l15  = lane & 15;
  const int quad = lane >> 4;
  const int wg   = blockIdx.x;
  const int grp  = (wg & 7) + ((wg >> 5) << 3);   // 0..127
  const int q    = (wg >> 3) & 3;
  const int b    = grp >> 1;
  const int mat  = grp & 1;
  const int j0   = q * 64;
  const _Float16* Kh = (mat ? khe : khs) + (size_t)b * (1024 * 256);
  const _Float16* Kl = (mat ? kle : kls) + (size_t)b * (1024 * 256);
  const _Float16* Tbh = Tgh + (size_t)((b * 2 + mat) * 16) * 4096;
  const _Float16* Tbl = Tgl + (size_t)((b * 2 + mat) * 16) * 4096;

  f32x4 S[16];
#pragma unroll
  for (int i = 0; i < 16; ++i) S[i] = {0.f, 0.f, 0.f, 0.f};

  for (int ck = 0; ck < 16; ++ck) {
    const int tok0 = ck * 64;

    float myw[4], mya[4], kvv[4][4];
#pragma unroll
    for (int r = 0; r < 4; ++r) {
      const int t = tok0 + wv * 16 + quad * 4 + r;
      const float4 sq = *(const float4*)(ssqP + ((size_t)mat * kTok + (size_t)b * 1024 + t) * 4);
      const float w = mat ? wts[t] : 1.f;
      myw[r] = w;
      mya[r] = w / (sq.x + sq.y + sq.z + sq.w + 1e-6f);
#pragma unroll
      for (int nt = 0; nt < 4; ++nt) {
        const size_t go = (size_t)t * 256 + j0 + nt * 16 + l15;
        kvv[r][nt] = (float)Kh[go] + (float)Kl[go];
      }
    }
    f16x8 tah[2], tal[2];
#pragma unroll
    for (int kit = 0; kit < 2; ++kit) {
      const size_t to = (size_t)ck * 4096 + (size_t)(wv * 16 + l15) * 64 + kit * 32 + quad * 8;
      tah[kit] = *(const f16x8*)(Tbh + to);
      tal[kit] = *(const f16x8*)(Tbl + to);
    }
    const _Float16* arow_h = Kh + (size_t)(tok0 + wv * 16 + l15) * 256 + quad * 8;
    const _Float16* arow_l = Kl + (size_t)(tok0 + wv * 16 + l15) * 256 + quad * 8;
    f16x8 a0h = *(const f16x8*)(arow_h);
    f16x8 a1h = *(const f16x8*)(arow_h + 32);
    f16x8 a0l = *(const f16x8*)(arow_l);
    f16x8 a1l = *(const f16x8*)(arow_l + 32);

#pragma unroll
    for (int nt = 0; nt < 4; ++nt) {
      const f32x4 v = S[0 * 4 + nt];
      union { _Float16 h[4]; uint2 u; } qh, ql;
#pragma unroll
      for (int r = 0; r < 4; ++r) fsplit(v[r], qh.h[r], ql.h[r]);
      const int ix = (nt * 16 + l15) * 72 + wv * 16 + quad * 4;
      *(uint2*)&Sb[0].h[ix] = qh.u;
      *(uint2*)&Sb[0].l[ix] = ql.u;
    }
    __syncthreads();   // BP0

    f32x4 Qa[4];
#pragma unroll
    for (int i = 0; i < 4; ++i) Qa[i] = {0.f, 0.f, 0.f, 0.f};
#pragma unroll
    for (int p = 0; p < 4; ++p) {
      const int cur = p & 1;
      f16x8 n0h, n1h, n0l, n1l;
      if (p < 3) {
        n0h = *(const f16x8*)(arow_h + (p + 1) * 64);
        n1h = *(const f16x8*)(arow_h + (p + 1) * 64 + 32);
        n0l = *(const f16x8*)(arow_l + (p + 1) * 64);
        n1l = *(const f16x8*)(arow_l + (p + 1) * 64 + 32);
#pragma unroll
        for (int nt = 0; nt < 4; ++nt) {
          const f32x4 v = S[(p + 1) * 4 + nt];
          union { _Float16 h[4]; uint2 u; } sh2, sl2;
#pragma unroll
          for (int r = 0; r < 4; ++r) fsplit(v[r], sh2.h[r], sl2.h[r]);
          const int ix = (nt * 16 + l15) * 72 + wv * 16 + quad * 4;
          *(uint2*)&Sb[1 - cur].h[ix] = sh2.u;
          *(uint2*)&Sb[1 - cur].l[ix] = sl2.u;
        }
      }
#pragma unroll
      for (int kit = 0; kit < 2; ++kit) {
        const f16x8 ah = kit ? a1h : a0h;
        const f16x8 al = kit ? a1l : a0l;
#pragma unroll
        for (int nt = 0; nt < 4; ++nt) {
          const int ix = (nt * 16 + l15) * 72 + kit * 32 + quad * 8;
          const f16x8 bh = *(const f16x8*)&Sb[cur].h[ix];
          const f16x8 bl = *(const f16x8*)&Sb[cur].l[ix];
          Qa[nt] = __builtin_amdgcn_mfma_f32_16x16x32_f16(ah, bh, Qa[nt], 0, 0, 0);
          Qa[nt] = __builtin_amdgcn_mfma_f32_16x16x32_f16(ah, bl, Qa[nt], 0, 0, 0);
          Qa[nt] = __builtin_amdgcn_mfma_f32_16x16x32_f16(al, bh, Qa[nt], 0, 0, 0);
        }
      }
      if (p < 3) {
        a0h = n0h; a1h = n1h; a0l = n0l; a1l = n1l;
        __syncthreads();   // dbuf WAR; p==3 barrier dropped (fenced by BY/BU/BP0)
      }
    }

#pragma unroll
    for (int nt = 0; nt < 4; ++nt) {
      union { _Float16 h[4]; uint2 u; } yh, yl;
#pragma unroll
      for (int r = 0; r < 4; ++r) {
        const float y = myw[r] * kvv[r][nt] - mya[r] * Qa[nt][r];
        fsplit(y, yh.h[r], yl.h[r]);
      }
      const int ix = (nt * 16 + l15) * 72 + wv * 16 + quad * 4;
      *(uint2*)&Yb.t.h[ix] = yh.u;
      *(uint2*)&Yb.t.l[ix] = yl.u;
    }
    __syncthreads();   // BY

    f32x4 Ua[4];
#pragma unroll
    for (int i = 0; i < 4; ++i) Ua[i] = {0.f, 0.f, 0.f, 0.f};
#pragma unroll
    for (int kit = 0; kit < 2; ++kit)
#pragma unroll
      for (int nt = 0; nt < 4; ++nt) {
        const int ix = (nt * 16 + l15) * 72 + kit * 32 + quad * 8;
        const f16x8 yh = *(const f16x8*)&Yb.t.h[ix];
        const f16x8 yl = *(const f16x8*)&Yb.t.l[ix];
        Ua[nt] = __builtin_amdgcn_mfma_f32_16x16x32_f16(tah[kit], yh, Ua[nt], 0, 0, 0);
        Ua[nt] = __builtin_amdgcn_mfma_f32_16x16x32_f16(tah[kit], yl, Ua[nt], 0, 0, 0);
        Ua[nt] = __builtin_amdgcn_mfma_f32_16x16x32_f16(tal[kit], yh, Ua[nt], 0, 0, 0);
      }
#pragma unroll
    for (int nt = 0; nt < 4; ++nt) {
      union { _Float16 h[4]; uint2 u; } uh, ul;
#pragma unroll
      for (int r = 0; r < 4; ++r) fsplit(Ua[nt][r], uh.h[r], ul.h[r]);
      const int ix = (nt * 16 + l15) * 72 + wv * 16 + quad * 4;
      *(uint2*)&Ub.h[ix] = uh.u;
      *(uint2*)&Ub.l[ix] = ul.u;
    }
    __syncthreads();   // BU

#pragma unroll
    for (int p = 0; p < 4; ++p) {
      union { _Float16 e[8]; f16x8 v; } kah[2], kal[2];
#pragma unroll
      for (int kit = 0; kit < 2; ++kit)
#pragma unroll
        for (int jj = 0; jj < 8; ++jj) {
          const size_t gko = (size_t)(tok0 + kit * 32 + quad * 8 + jj) * 256
                           + p * 64 + wv * 16 + l15;
          kah[kit].e[jj] = Kh[gko];
          kal[kit].e[jj] = Kl[gko];
        }
#pragma unroll
      for (int kit = 0; kit < 2; ++kit)
#pragma unroll
        for (int nt = 0; nt < 4; ++nt) {
          const int ix = (nt * 16 + l15) * 72 + kit * 32 + quad * 8;
          const f16x8 ubh = *(const f16x8*)&Ub.h[ix];
          const f16x8 ubl = *(const f16x8*)&Ub.l[ix];
          f32x4 s = S[p * 4 + nt];
          s = __builtin_amdgcn_mfma_f32_16x16x32_f16(kah[kit].v, ubh, s, 0, 0, 0);
          s = __builtin_amdgcn_mfma_f32_16x16x32_f16(kah[kit].v, ubl, s, 0, 0, 0);
          s = __builtin_amdgcn_mfma_f32_16x16x32_f16(kal[kit].v, ubh, s, 0, 0, 0);
          S[p * 4 + nt] = s;
        }
    }
    // next chunk's BP0 orders Ub WAR and Sb reuse
  }

  float part[4] = {0.f, 0.f, 0.f, 0.f};
  const size_t lastoff = (size_t)(kL - 1) * 256;
#pragma unroll
  for (int p = 0; p < 4; ++p) {
    float klr[4];
#pragma unroll
    for (int r = 0; r < 4; ++r) {
      const int row = p * 64 + wv * 16 + quad * 4 + r;
      klr[r] = (float)Kh[lastoff + row] + (float)Kl[lastoff + row];
    }
#pragma unroll
    for (int nt = 0; nt < 4; ++nt)
#pragma unroll
      for (int r = 0; r < 4; ++r) part[nt] += S[p * 4 + nt][r] * klr[r];
  }
#pragma unroll
  for (int nt = 0; nt < 4; ++nt) {
    part[nt] += __shfl_xor(part[nt], 16);
    part[nt] += __shfl_xor(part[nt], 32);
  }
  __syncthreads();
  if (lane < 16) {
#pragma unroll
    for (int nt = 0; nt < 4; ++nt) Yb.cred[wv][nt * 16 + l15] = part[nt];
  }
  __syncthreads();
  if (tid < 64) {
    const float c = Yb.cred[0][tid] + Yb.cred[1][tid] + Yb.cred[2][tid] + Yb.cred[3][tid];
    c_out[(size_t)b * 512 + mat * 256 + j0 + tid] = c;
  }
}

// ---------------- output GEMM: (64 x 512) @ (512 x 32000) + out_b -> fp32
__global__ __launch_bounds__(256) void out_gemm(
    const float* __restrict__ A, const float* __restrict__ Bm,
    const float* __restrict__ bias, float* __restrict__ C)
{
  __shared__ float As[16][64];
  __shared__ float Bs[16][128];
  const int tid = threadIdx.x;
  const int bn0 = blockIdx.x * 128;
  const int tm = tid >> 4, tn = tid & 15;
  float acc[4][8];
#pragma unroll
  for (int i = 0; i < 4; ++i)
#pragma unroll
    for (int j = 0; j < 8; ++j) acc[i][j] = 0.f;

  const int am  = tid & 63;
  const int ak  = (tid >> 6) * 4;
  const int bkr = tid >> 5;
  const int bcg = (tid & 31) * 4;

  for (int k0 = 0; k0 < kH; k0 += 16) {
    const float4 a0 = *(const float4*)(A + (size_t)am * kH + k0 + ak);
    const float4 b0 = *(const float4*)(Bm + (size_t)(k0 + bkr) * kV + bn0 + bcg);
    const float4 b1 = *(const float4*)(Bm + (size_t)(k0 + bkr + 8) * kV + bn0 + bcg);
    __syncthreads();
    As[ak + 0][am] = a0.x; As[ak + 1][am] = a0.y;
    As[ak + 2][am] = a0.z; As[ak + 3][am] = a0.w;
    *(float4*)&Bs[bkr][bcg]     = b0;
    *(float4*)&Bs[bkr + 8][bcg] = b1;
    __syncthreads();
#pragma unroll
    for (int kk = 0; kk < 16; ++kk) {
      const float4 aA = *(const float4*)&As[kk][tm * 4];
      const float4 bA = *(const float4*)&Bs[kk][tn * 4];
      const float4 bB = *(const float4*)&Bs[kk][64 + tn * 4];
      const float av[4] = {aA.x, aA.y, aA.z, aA.w};
      const float bv[8] = {bA.x, bA.y, bA.z, bA.w, bB.x, bB.y, bB.z, bB.w};
#pragma unroll
      for (int i = 0; i < 4; ++i)
#pragma unroll
        for (int j = 0; j < 8; ++j) acc[i][j] += av[i] * bv[j];
    }
  }

#pragma unroll
  for (int i = 0; i < 4; ++i) {
    const int row = tm * 4 + i;
#pragma unroll
    for (int hh = 0; hh < 2; ++hh) {
      const int n0 = bn0 + tn * 4 + hh * 64;
      const float4 bb = *(const float4*)(bias + n0);
      float4 o;
      o.x = acc[i][hh * 4 + 0] + bb.x;
      o.y = acc[i][hh * 4 + 1] + bb.y;
      o.z = acc[i][hh * 4 + 2] + bb.z;
      o.w = acc[i][hh * 4 + 3] + bb.w;
      *(float4*)(C + (size_t)row * kV + n0) = o;
    }
  }
}

}  // namespace

extern "C" void kernel_launch(void* const* d_in, const int* in_sizes, int n_in,
                              void* d_out, int out_size, void* d_ws, size_t ws_size,
                              hipStream_t stream)
{
  const int*   seq     = (const int*)  d_in[0];
  const float* embed   = (const float*)d_in[1];
  const float* w1      = (const float*)d_in[2];
  const float* b1      = (const float*)d_in[3];
  const float* w2      = (const float*)d_in[4];
  const float* b2      = (const float*)d_in[5];
  const float* ln_g    = (const float*)d_in[6];
  const float* ln_b    = (const float*)d_in[7];
  const float* sem_w   = (const float*)d_in[8];
  const float* sem_b   = (const float*)d_in[9];
  const float* epi_w   = (const float*)d_in[10];
  const float* epi_b   = (const float*)d_in[11];
  const float* out_w   = (const float*)d_in[12];
  const float* out_b   = (const float*)d_in[13];
  const float* pos_emb = (const float*)d_in[14];
  const float* pos_w   = (const float*)d_in[15];
  const float* pos_b   = (const float*)d_in[16];
  float* out = (float*)d_out;

  const int chunkN = (ws_size >= (size_t)240500000) ? 16384 : 8192;
  const int nch    = kTok / chunkN;
  const int nyb    = chunkN / 1024;   // Ny/8 = (chunkN/128)/8
  const int tband  = chunkN / 8;
  // emb16 adds 32.8 MB; enable only when ws clearly fits (deterministic).
  const int useE16 = (ws_size >= (size_t)285000000) ? 1 : 0;

  char* p = (char*)d_ws;
  _Float16* w1th = (_Float16*)p; p += (size_t)1024 * 512 * 2;
  _Float16* w1tl = (_Float16*)p; p += (size_t)1024 * 512 * 2;   // unused (PROD=1)
  _Float16* w2th = (_Float16*)p; p += (size_t)512 * 1024 * 2;
  _Float16* w2tl = (_Float16*)p; p += (size_t)512 * 1024 * 2;   // unused (PROD=1)
  _Float16* wseh = (_Float16*)p; p += (size_t)512 * 512 * 2;
  _Float16* wsel = (_Float16*)p; p += (size_t)512 * 512 * 2;
  _Float16* t1h  = (_Float16*)p; p += (size_t)chunkN * 1024 * 2;
  _Float16* t1l  = (_Float16*)p; p += (size_t)chunkN * 1024 * 2;   // (spare; T-lo alias)
  float*    x    = (float*)p;    p += (size_t)chunkN * kH * 4;
  _Float16* khs  = (_Float16*)p; p += (size_t)kTok * kHalf * 2;   // K hi/lo fp16
  _Float16* kls  = (_Float16*)p; p += (size_t)kTok * kHalf * 2;
  _Float16* khe  = (_Float16*)p; p += (size_t)kTok * kHalf * 2;
  _Float16* kle  = (_Float16*)p; p += (size_t)kTok * kHalf * 2;
  float*    wts  = (float*)p;    p += (size_t)kL * 4;
  float*    cout_= (float*)p;    p += (size_t)kB * 512 * 4;
  float*    ssqp = (float*)p;    p += (size_t)2 * kTok * 4 * 4;   // [mat][tok][4] partials
  _Float16* emb16= (_Float16*)p; p += (size_t)kV * kH * 2;        // used iff useE16
  _Float16* hh   = t1h;          // alias: t1 dead once x is written
  _Float16* Tgh = t1h;           // T aliases t1 (dead after chunk loop)
  _Float16* Tgl = t1l;

  pos_kernel<<<dim3((kL + 255) / 256), dim3(256), 0, stream>>>(pos_emb, pos_w, pos_b, wts);
  if (useE16)
    emb_half<<<dim3(kV * kH / 2048), dim3(256), 0, stream>>>(embed, emb16);
  transpose_split<<<dim3(1024 * 512 / 256), dim3(256), 0, stream>>>(w1, w1th, w1tl, 1024, 9);
  transpose_split<<<dim3(512 * 1024 / 256), dim3(256), 0, stream>>>(w2, w2th, w2tl, 512, 10);
  transpose_split<<<dim3(256 * 512 / 256), dim3(256), 0, stream>>>(sem_w, wseh, wsel, 256, 9);
  transpose_split<<<dim3(256 * 512 / 256), dim3(256), 0, stream>>>(
      epi_w, wseh + (size_t)256 * 512, wsel + (size_t)256 * 512, 256, 9);

  for (int c = 0; c < nch; ++c) {
    const int tok0 = c * chunkN;
    if (useE16)
      hgemm<0, 1, 1><<<dim3((1024 / 128) * (chunkN / 128)), dim3(256), 0, stream>>>(
          seq, embed, emb16, w1th, nullptr, b1, nullptr,
          nullptr, t1h, nullptr, nullptr, nullptr, 512, 1024, tok0, nyb);
    else
      hgemm<0, 1, 0><<<dim3((1024 / 128) * (chunkN / 128)), dim3(256), 0, stream>>>(
          seq, embed, nullptr, w1th, nullptr, b1, nullptr,
          nullptr, t1h, nullptr, nullptr, nullptr, 512, 1024, tok0, nyb);
    hgemm<1, 1><<<dim3((512 / 128) * (chunkN / 128)), dim3(256), 0, stream>>>(
        seq, embed, t1h, w2th, nullptr, b2, nullptr,
        x, nullptr, nullptr, nullptr, nullptr, 1024, 512, tok0, nyb);
    ln_split<<<dim3(chunkN / 4), dim3(256), 0, stream>>>(x, ln_g, ln_b, hh, tband);
    hgemm<2, 2><<<dim3((512 / 128) * (chunkN / 128)), dim3(256), 0, stream>>>(
        seq, embed, hh, wseh, wsel, sem_b, epi_b,
        ssqp, kls, kle, (float*)khs, (float*)khe,
        512, 512, tok0, nyb);
  }

  tinv_kernel<<<dim3(2048), dim3(64), 0, stream>>>(
      khs, kls, khe, kle, ssqp, wts, Tgh, Tgl);
  scan_chunked<<<dim3(512), dim3(256), 0, stream>>>(
      khs, kls, khe, kle, ssqp, wts, Tgh, Tgl, cout_);
  out_gemm<<<dim3(kV / 128), dim3(256), 0, stream>>>(cout_, out_w, out_b, out);

  (void)in_sizes; (void)n_in; (void)out_size;
}